// Round 1
// baseline (680.835 us; speedup 1.0000x reference)
//
#include <hip/hip_runtime.h>
#include <cstdint>

#define LRELU(a) ((a) > 0.f ? (a) : 0.2f * (a))

// ---------------- histogram of dst + edge_type ----------------
__global__ __launch_bounds__(256) void hist_kernel(const int* __restrict__ ei,
                                                   const int* __restrict__ etype, int E,
                                                   int* __restrict__ counts,
                                                   int* __restrict__ counts10) {
    __shared__ int lh[16];
    int t = threadIdx.x;
    if (t < 16) lh[t] = 0;
    __syncthreads();
    int e = blockIdx.x * 256 + t;
    if (e < E) {
        int d = ei[E + e];          // dst row
        atomicAdd(&counts[d], 1);
        atomicAdd(&lh[etype[e]], 1);
    }
    __syncthreads();
    if (t < 16 && lh[t]) atomicAdd(&counts10[t], lh[t]);
}

// ---------------- per-edge-type attention-logit table ----------------
// alphaE[l][t][h] = sum_c (lin_e_w @ emb[t])[h,c] * a_e[h,c]; slot t=10 = mean row
__global__ void alphaE_kernel(const float* __restrict__ emb,
                              const float* __restrict__ w0, const float* __restrict__ ae0,
                              const float* __restrict__ w1, const float* __restrict__ ae1,
                              const int* __restrict__ counts10, int E,
                              float* __restrict__ alphaE) {
    int t = threadIdx.x;
    __shared__ float tmp[88];
    if (t < 80) {
        int l = t / 40, r = t % 40, ty = r >> 2, h = r & 3;
        const float* w = l ? w1 : w0;
        const float* ae = l ? ae1 : ae0;
        int C = l ? 8 : 16;
        const float* ev = emb + ty * 16;
        float val = 0.f;
        for (int c = 0; c < C; ++c) {
            const float* wr = w + (h * C + c) * 16;
            float s = 0.f;
            for (int d = 0; d < 16; ++d) s += wr[d] * ev[d];
            val += s * ae[h * C + c];
        }
        tmp[l * 44 + ty * 4 + h] = val;
        alphaE[l * 44 + ty * 4 + h] = val;
    }
    __syncthreads();
    if (t < 8) {
        int l = t >> 2, h = t & 3;
        float s = 0.f;
        for (int ty = 0; ty < 10; ++ty) s += (float)counts10[ty] * tmp[l * 44 + ty * 4 + h];
        alphaE[l * 44 + 40 + h] = s / (float)E;
    }
}

// ---------------- exclusive scan (3 kernels) ----------------
__global__ __launch_bounds__(256) void scan1(const int* __restrict__ counts, int N,
                                             int* __restrict__ partials) {
    __shared__ int sd[256];
    int t = threadIdx.x, i = blockIdx.x * 256 + t;
    sd[t] = (i < N) ? counts[i] : 0;
    __syncthreads();
    for (int off = 128; off > 0; off >>= 1) {
        if (t < off) sd[t] += sd[t + off];
        __syncthreads();
    }
    if (t == 0) partials[blockIdx.x] = sd[0];
}

__global__ void scan2(int* __restrict__ partials, int nblk, int* __restrict__ rowptr, int N) {
    if (threadIdx.x == 0) {
        int run = 0;
        for (int b = 0; b < nblk; ++b) { int v = partials[b]; partials[b] = run; run += v; }
        rowptr[N] = run;
    }
}

__global__ __launch_bounds__(256) void scan3(const int* __restrict__ counts, int N,
                                             const int* __restrict__ partials,
                                             int* __restrict__ rowptr, int* __restrict__ cursor) {
    __shared__ int sd[256];
    int t = threadIdx.x, i = blockIdx.x * 256 + t;
    int v = (i < N) ? counts[i] : 0;
    sd[t] = v;
    __syncthreads();
    for (int off = 1; off < 256; off <<= 1) {
        int add = (t >= off) ? sd[t - off] : 0;
        __syncthreads();
        sd[t] += add;
        __syncthreads();
    }
    int val = partials[blockIdx.x] + sd[t] - v;
    if (i < N) { rowptr[i] = val; cursor[i] = val; }
}

// ---------------- scatter edges into CSR (packed src|type) ----------------
__global__ __launch_bounds__(256) void scatter_kernel(const int* __restrict__ ei,
                                                      const int* __restrict__ etype, int E,
                                                      int* __restrict__ cursor,
                                                      int* __restrict__ packed) {
    int e = blockIdx.x * 256 + threadIdx.x;
    if (e >= E) return;
    int s = ei[e], d = ei[E + e], ty = etype[e];
    int pos = atomicAdd(&cursor[d], 1);
    packed[pos] = s | (ty << 17);   // N=100000 < 2^17
}

// ---------------- h = x @ W^T  (W: [OUT,64] row-major) ----------------
template <int OUT>
__global__ __launch_bounds__(256) void gemm_kernel(const float* __restrict__ x,
                                                   const float* __restrict__ W, int N,
                                                   float* __restrict__ out) {
    __shared__ float wt[64 * (OUT + 1)];
    __shared__ float xs[32 * 64];
    int t = threadIdx.x;
    for (int idx = t; idx < OUT * 64; idx += 256) {
        int j = idx >> 6, k = idx & 63;
        wt[k * (OUT + 1) + j] = W[idx];
    }
    int rowbase = blockIdx.x * 32;
    int nrows = min(32, N - rowbase);
    for (int idx = t; idx < nrows * 64; idx += 256) xs[idx] = x[rowbase * 64 + idx];
    __syncthreads();
    int j = t % OUT;
    int rg = t / OUT;
    const int NG = 256 / OUT;
    for (int r = rg; r < nrows; r += NG) {
        float acc = 0.f;
        const float* xr = xs + r * 64;
#pragma unroll
        for (int k = 0; k < 64; ++k) acc += xr[k] * wt[k * (OUT + 1) + j];
        out[(size_t)(rowbase + r) * OUT + j] = acc;
    }
}

// ---------------- per-(node,head) attention scores ----------------
template <int C>
__global__ __launch_bounds__(256) void score_kernel(const float* __restrict__ h,
                                                    const float* __restrict__ asrc,
                                                    const float* __restrict__ adst, int N,
                                                    float* __restrict__ ssrc,
                                                    float* __restrict__ sdst) {
    int t = blockIdx.x * 256 + threadIdx.x;
    if (t >= N * 4) return;
    int hd = t & 3;
    const float* hr = h + (size_t)t * C;
    float s1 = 0.f, s2 = 0.f;
#pragma unroll
    for (int c = 0; c < C; ++c) { float v = hr[c]; s1 += v * asrc[hd * C + c]; s2 += v * adst[hd * C + c]; }
    ssrc[t] = s1;
    sdst[t] = s2;
}

// ---------------- per-(node,head) softmax-aggregate (2-pass, CSR gather) ----------------
template <int C, bool RELU>
__global__ __launch_bounds__(256) void agg_kernel(const int* __restrict__ rowptr,
                                                  const int* __restrict__ packed,
                                                  const float* __restrict__ hmat,
                                                  const float* __restrict__ ssrc,
                                                  const float* __restrict__ sdst,
                                                  const float* __restrict__ alphaE,
                                                  const float* __restrict__ bias, int N,
                                                  float* __restrict__ out) {
    __shared__ float aE[44];
    if (threadIdx.x < 44) aE[threadIdx.x] = alphaE[threadIdx.x];
    __syncthreads();
    int t = blockIdx.x * 256 + threadIdx.x;
    if (t >= N * 4) return;
    int node = t >> 2, hd = t & 3;
    int beg = rowptr[node], end = rowptr[node + 1];
    float sd = sdst[t];
    float a_self = LRELU(ssrc[t] + sd + aE[40 + hd]);
    float m = a_self;
    for (int k = beg; k < end; ++k) {
        int p = packed[k];
        int s = p & 131071, ty = p >> 17;
        float a = LRELU(ssrc[s * 4 + hd] + sd + aE[ty * 4 + hd]);
        m = fmaxf(m, a);
    }
    float denom = __expf(a_self - m);
    float acc[C];
    const float* hn = hmat + (size_t)t * C;
#pragma unroll
    for (int c = 0; c < C; ++c) acc[c] = denom * hn[c];
    for (int k = beg; k < end; ++k) {
        int p = packed[k];
        int s = p & 131071, ty = p >> 17;
        float a = LRELU(ssrc[s * 4 + hd] + sd + aE[ty * 4 + hd]);
        float ex = __expf(a - m);
        denom += ex;
        const float4* hs = (const float4*)(hmat + (size_t)(s * 4 + hd) * C);
#pragma unroll
        for (int c4 = 0; c4 < C / 4; ++c4) {
            float4 v = hs[c4];
            acc[c4 * 4 + 0] += ex * v.x;
            acc[c4 * 4 + 1] += ex * v.y;
            acc[c4 * 4 + 2] += ex * v.z;
            acc[c4 * 4 + 3] += ex * v.w;
        }
    }
    float inv = 1.f / denom;
    float* op = out + (size_t)node * (4 * C) + hd * C;
#pragma unroll
    for (int c = 0; c < C; ++c) {
        float o = fmaf(acc[c], inv, bias[hd * C + c]);
        if (RELU) o = fmaxf(o, 0.f);
        op[c] = o;
    }
}

extern "C" void kernel_launch(void* const* d_in, const int* in_sizes, int n_in,
                              void* d_out, int out_size, void* d_ws, size_t ws_size,
                              hipStream_t stream) {
    const float* x    = (const float*)d_in[0];
    const int*   ei   = (const int*)d_in[1];
    const int*   ety  = (const int*)d_in[2];
    const float* emb  = (const float*)d_in[3];
    const float* w0   = (const float*)d_in[4];
    const float* as0  = (const float*)d_in[5];
    const float* ad0  = (const float*)d_in[6];
    const float* we0  = (const float*)d_in[7];
    const float* ae0  = (const float*)d_in[8];
    const float* b0   = (const float*)d_in[9];
    const float* w1   = (const float*)d_in[10];
    const float* as1  = (const float*)d_in[11];
    const float* ad1  = (const float*)d_in[12];
    const float* we1  = (const float*)d_in[13];
    const float* ae1  = (const float*)d_in[14];
    const float* b1   = (const float*)d_in[15];

    const int N = in_sizes[0] / 64;
    const int E = in_sizes[1] / 2;
    const int nblk = (N + 255) / 256;

    char* ws = (char*)d_ws;
    size_t o = 0;
    auto alloc = [&](size_t bytes) { size_t r = o; o = (o + bytes + 255) & ~(size_t)255; return r; };
    size_t o_counts   = alloc((size_t)4 * N);
    size_t o_rowptr   = alloc((size_t)4 * (N + 1));
    size_t o_cursor   = alloc((size_t)4 * N);
    size_t o_partials = alloc((size_t)4 * nblk);
    size_t o_counts10 = alloc(64);
    size_t o_alphaE   = alloc(4 * 88);
    size_t o_packed   = alloc((size_t)4 * E);
    size_t o_h0       = alloc((size_t)4 * N * 64);   // reused as h1 ([N,32]) for layer 1
    size_t o_x1       = alloc((size_t)4 * N * 64);
    size_t o_ssrc     = alloc((size_t)4 * N * 4);
    size_t o_sdst     = alloc((size_t)4 * N * 4);
    (void)ws_size;

    int*   counts   = (int*)(ws + o_counts);
    int*   rowptr   = (int*)(ws + o_rowptr);
    int*   cursor   = (int*)(ws + o_cursor);
    int*   partials = (int*)(ws + o_partials);
    int*   counts10 = (int*)(ws + o_counts10);
    float* alphaE   = (float*)(ws + o_alphaE);
    int*   packed   = (int*)(ws + o_packed);
    float* h0       = (float*)(ws + o_h0);
    float* x1       = (float*)(ws + o_x1);
    float* ssrc     = (float*)(ws + o_ssrc);
    float* sdst     = (float*)(ws + o_sdst);
    float* outp     = (float*)d_out;

    hipMemsetAsync(counts, 0, (size_t)4 * N, stream);
    hipMemsetAsync(counts10, 0, 64, stream);

    int egrid = (E + 255) / 256;
    hist_kernel<<<egrid, 256, 0, stream>>>(ei, ety, E, counts, counts10);
    alphaE_kernel<<<1, 128, 0, stream>>>(emb, we0, ae0, we1, ae1, counts10, E, alphaE);
    scan1<<<nblk, 256, 0, stream>>>(counts, N, partials);
    scan2<<<1, 64, 0, stream>>>(partials, nblk, rowptr, N);
    scan3<<<nblk, 256, 0, stream>>>(counts, N, partials, rowptr, cursor);
    scatter_kernel<<<egrid, 256, 0, stream>>>(ei, ety, E, cursor, packed);

    int ngrid32 = (N + 31) / 32;
    int tgrid = (N * 4 + 255) / 256;

    // Layer 0: in=64, H=4, C=16
    gemm_kernel<64><<<ngrid32, 256, 0, stream>>>(x, w0, N, h0);
    score_kernel<16><<<tgrid, 256, 0, stream>>>(h0, as0, ad0, N, ssrc, sdst);
    agg_kernel<16, true><<<tgrid, 256, 0, stream>>>(rowptr, packed, h0, ssrc, sdst,
                                                    alphaE, b0, N, x1);
    // Layer 1: in=64, H=4, C=8
    gemm_kernel<32><<<ngrid32, 256, 0, stream>>>(x1, w1, N, h0);
    score_kernel<8><<<tgrid, 256, 0, stream>>>(h0, as1, ad1, N, ssrc, sdst);
    agg_kernel<8, false><<<tgrid, 256, 0, stream>>>(rowptr, packed, h0, ssrc, sdst,
                                                    alphaE + 44, b1, N, outp);
}

// Round 2
// 405.708 us; speedup vs baseline: 1.6781x; 1.6781x over previous
//
#include <hip/hip_runtime.h>
#include <cstdint>

#define LRELU(a) ((a) > 0.f ? (a) : 0.2f * (a))
#define BBITS 9                      // 512 nodes per bucket
#define BSZ   (1 << BBITS)
#define MAXB  256                    // max buckets (N=100000 -> 196)

// ---------------- K1: bucket histogram + edge-type histogram ----------------
__global__ __launch_bounds__(256) void k1_bucket_hist(const int* __restrict__ ei,
                                                      const int* __restrict__ ety, int E,
                                                      int* __restrict__ bcount,
                                                      int* __restrict__ counts10) {
    __shared__ int lh[MAXB];
    __shared__ int lt[16];
    int t = threadIdx.x;
    for (int i = t; i < MAXB; i += 256) lh[i] = 0;
    if (t < 16) lt[t] = 0;
    __syncthreads();
    int base = blockIdx.x * 4096;
    int cnt = min(4096, E - base);
    for (int i = t; i < cnt; i += 256) {
        atomicAdd(&lh[ei[E + base + i] >> BBITS], 1);
        atomicAdd(&lt[ety[base + i]], 1);
    }
    __syncthreads();
    for (int i = t; i < MAXB; i += 256) if (lh[i]) atomicAdd(&bcount[i], lh[i]);
    if (t < 16 && lt[t]) atomicAdd(&counts10[t], lt[t]);
}

// ---------------- K2: scan bucket counts (one block) ----------------
__global__ __launch_bounds__(256) void k2_scan(const int* __restrict__ bcount, int NB,
                                               int* __restrict__ bbase,
                                               int* __restrict__ bcursor,
                                               int* __restrict__ rowptr, int N, int E) {
    __shared__ int sc[256], orig[256];
    int t = threadIdx.x;
    int v = (t < NB) ? bcount[t] : 0;
    orig[t] = v;
    sc[t] = v;
    __syncthreads();
    for (int off = 1; off < 256; off <<= 1) {
        int a = (t >= off) ? sc[t - off] : 0;
        __syncthreads();
        sc[t] += a;
        __syncthreads();
    }
    int ex = sc[t] - orig[t];
    bbase[t] = ex;          // for t in [NB,256): ex == total E (v==0 above NB)
    bcursor[t] = ex;
    if (t == 0) rowptr[N] = E;
}

// ---------------- K3: coarse-bucket scatter with chunked coalesced append ----------------
__global__ __launch_bounds__(256) void k3_bucket_scatter(const int* __restrict__ ei,
                                                         const int* __restrict__ ety, int E,
                                                         int* __restrict__ bcursor,
                                                         int* __restrict__ staging) {
    __shared__ int ent[4096];
    __shared__ unsigned char ebb[4096];
    __shared__ int lh[MAXB], lstart[MAXB], lcur[MAXB], cbase[MAXB], sc[MAXB];
    int t = threadIdx.x;
    lh[t] = 0;
    __syncthreads();
    int base = blockIdx.x * 4096;
    int cnt = min(4096, E - base);
    // pass 1: local bucket histogram
    for (int i = t; i < cnt; i += 256) atomicAdd(&lh[ei[E + base + i] >> BBITS], 1);
    __syncthreads();
    // exclusive scan of lh
    sc[t] = lh[t];
    __syncthreads();
    for (int off = 1; off < 256; off <<= 1) {
        int a = (t >= off) ? sc[t - off] : 0;
        __syncthreads();
        sc[t] += a;
        __syncthreads();
    }
    lstart[t] = sc[t] - lh[t];
    // reserve contiguous chunk in global staging per bucket
    int c = lh[t];
    cbase[t] = c ? atomicAdd(&bcursor[t], c) : 0;
    lcur[t] = sc[t] - lh[t];
    __syncthreads();
    // pass 2: re-read edges, scatter into LDS grouped by bucket
    for (int i = t; i < cnt; i += 256) {
        int s = ei[base + i], d = ei[E + base + i], ty = ety[base + i];
        int b = d >> BBITS;
        int pos = atomicAdd(&lcur[b], 1);
        ent[pos] = s | (ty << 17) | ((d & (BSZ - 1)) << 21);
        ebb[pos] = (unsigned char)b;
    }
    __syncthreads();
    // coalesced-run writeout
    for (int i = t; i < cnt; i += 256) {
        int b = ebb[i];
        staging[cbase[b] + (i - lstart[b])] = ent[i];
    }
}

// ---------------- K4: per-bucket CSR build (rowptr + node-grouped packed) ----------------
__global__ __launch_bounds__(512) void k4_bucket_build(const int* __restrict__ bbase,
                                                       const int* __restrict__ staging, int N,
                                                       int* __restrict__ rowptr,
                                                       int* __restrict__ packed) {
    __shared__ int lcnt[BSZ], lsc[BSZ], lcur[BSZ];
    int b = blockIdx.x;
    int t = threadIdx.x;
    int base = bbase[b], cnt = bbase[b + 1] - base;
    int n0 = b << BBITS;
    lcnt[t] = 0;
    __syncthreads();
    for (int i = t; i < cnt; i += 512) atomicAdd(&lcnt[staging[base + i] >> 21], 1);
    __syncthreads();
    lsc[t] = lcnt[t];
    __syncthreads();
    for (int off = 1; off < BSZ; off <<= 1) {
        int a = (t >= off) ? lsc[t - off] : 0;
        __syncthreads();
        lsc[t] += a;
        __syncthreads();
    }
    int lstart = lsc[t] - lcnt[t];
    lcur[t] = lstart;
    int node = n0 + t;
    if (node < N) rowptr[node] = base + lstart;
    __syncthreads();
    for (int i = t; i < cnt; i += 512) {
        int entry = staging[base + i];
        int pos = atomicAdd(&lcur[entry >> 21], 1);
        packed[base + pos] = entry & 0x1FFFFF;   // src | type<<17
    }
}

// ---------------- per-edge-type attention-logit table ----------------
__global__ void alphaE_kernel(const float* __restrict__ emb,
                              const float* __restrict__ w0, const float* __restrict__ ae0,
                              const float* __restrict__ w1, const float* __restrict__ ae1,
                              const int* __restrict__ counts10, int E,
                              float* __restrict__ alphaE) {
    int t = threadIdx.x;
    __shared__ float tmp[88];
    if (t < 80) {
        int l = t / 40, r = t % 40, ty = r >> 2, h = r & 3;
        const float* w = l ? w1 : w0;
        const float* ae = l ? ae1 : ae0;
        int C = l ? 8 : 16;
        const float* ev = emb + ty * 16;
        float val = 0.f;
        for (int c = 0; c < C; ++c) {
            const float* wr = w + (h * C + c) * 16;
            float s = 0.f;
            for (int d = 0; d < 16; ++d) s += wr[d] * ev[d];
            val += s * ae[h * C + c];
        }
        tmp[l * 44 + ty * 4 + h] = val;
        alphaE[l * 44 + ty * 4 + h] = val;
    }
    __syncthreads();
    if (t < 8) {
        int l = t >> 2, h = t & 3;
        float s = 0.f;
        for (int ty = 0; ty < 10; ++ty) s += (float)counts10[ty] * tmp[l * 44 + ty * 4 + h];
        alphaE[l * 44 + 40 + h] = s / (float)E;
    }
}

// ---------------- h = x @ W^T  (W: [OUT,64] row-major) ----------------
template <int OUT>
__global__ __launch_bounds__(256) void gemm_kernel(const float* __restrict__ x,
                                                   const float* __restrict__ W, int N,
                                                   float* __restrict__ out) {
    __shared__ float wt[64 * (OUT + 1)];
    __shared__ float xs[32 * 64];
    int t = threadIdx.x;
    for (int idx = t; idx < OUT * 64; idx += 256) {
        int j = idx >> 6, k = idx & 63;
        wt[k * (OUT + 1) + j] = W[idx];
    }
    int rowbase = blockIdx.x * 32;
    int nrows = min(32, N - rowbase);
    for (int idx = t; idx < nrows * 64; idx += 256) xs[idx] = x[rowbase * 64 + idx];
    __syncthreads();
    int j = t % OUT;
    int rg = t / OUT;
    const int NG = 256 / OUT;
    for (int r = rg; r < nrows; r += NG) {
        float acc = 0.f;
        const float* xr = xs + r * 64;
#pragma unroll
        for (int k = 0; k < 64; ++k) acc += xr[k] * wt[k * (OUT + 1) + j];
        out[(size_t)(rowbase + r) * OUT + j] = acc;
    }
}

// ---------------- per-(node,head) attention scores ----------------
template <int C>
__global__ __launch_bounds__(256) void score_kernel(const float* __restrict__ h,
                                                    const float* __restrict__ asrc,
                                                    const float* __restrict__ adst, int N,
                                                    float* __restrict__ ssrc,
                                                    float* __restrict__ sdst) {
    int t = blockIdx.x * 256 + threadIdx.x;
    if (t >= N * 4) return;
    int hd = t & 3;
    const float* hr = h + (size_t)t * C;
    float s1 = 0.f, s2 = 0.f;
#pragma unroll
    for (int c = 0; c < C; ++c) { float v = hr[c]; s1 += v * asrc[hd * C + c]; s2 += v * adst[hd * C + c]; }
    ssrc[t] = s1;
    sdst[t] = s2;
}

// ---------------- per-(node,head) online-softmax aggregate (1 pass) ----------------
template <int C, bool RELU>
__global__ __launch_bounds__(256) void agg_kernel(const int* __restrict__ rowptr,
                                                  const int* __restrict__ packed,
                                                  const float* __restrict__ hmat,
                                                  const float* __restrict__ ssrc,
                                                  const float* __restrict__ sdst,
                                                  const float* __restrict__ alphaE,
                                                  const float* __restrict__ bias, int N,
                                                  float* __restrict__ out) {
    __shared__ float aE[44];
    if (threadIdx.x < 44) aE[threadIdx.x] = alphaE[threadIdx.x];
    __syncthreads();
    int t = blockIdx.x * 256 + threadIdx.x;
    if (t >= N * 4) return;
    int node = t >> 2, hd = t & 3;
    int beg = rowptr[node], end = rowptr[node + 1];
    float sd = sdst[t];
    // self-loop seeds the online softmax: m = a_self, weight exp(0)=1
    float m = LRELU(ssrc[t] + sd + aE[40 + hd]);
    float denom = 1.f;
    float acc[C];
    const float* hn = hmat + (size_t)t * C;
#pragma unroll
    for (int c = 0; c < C; ++c) acc[c] = hn[c];
    for (int k = beg; k < end; ++k) {
        int p = packed[k];
        int s = p & 131071, ty = (p >> 17) & 15;
        float a = LRELU(ssrc[s * 4 + hd] + sd + aE[ty * 4 + hd]);
        float ex;
        if (a > m) {
            float r = __expf(m - a);
            denom *= r;
#pragma unroll
            for (int c = 0; c < C; ++c) acc[c] *= r;
            m = a;
            ex = 1.f;
        } else {
            ex = __expf(a - m);
        }
        denom += ex;
        const float4* hs = (const float4*)(hmat + (size_t)(s * 4 + hd) * C);
#pragma unroll
        for (int c4 = 0; c4 < C / 4; ++c4) {
            float4 v = hs[c4];
            acc[c4 * 4 + 0] += ex * v.x;
            acc[c4 * 4 + 1] += ex * v.y;
            acc[c4 * 4 + 2] += ex * v.z;
            acc[c4 * 4 + 3] += ex * v.w;
        }
    }
    float inv = 1.f / denom;
    float* op = out + (size_t)node * (4 * C) + hd * C;
#pragma unroll
    for (int c = 0; c < C; ++c) {
        float o = fmaf(acc[c], inv, bias[hd * C + c]);
        if (RELU) o = fmaxf(o, 0.f);
        op[c] = o;
    }
}

extern "C" void kernel_launch(void* const* d_in, const int* in_sizes, int n_in,
                              void* d_out, int out_size, void* d_ws, size_t ws_size,
                              hipStream_t stream) {
    const float* x    = (const float*)d_in[0];
    const int*   ei   = (const int*)d_in[1];
    const int*   ety  = (const int*)d_in[2];
    const float* emb  = (const float*)d_in[3];
    const float* w0   = (const float*)d_in[4];
    const float* as0  = (const float*)d_in[5];
    const float* ad0  = (const float*)d_in[6];
    const float* we0  = (const float*)d_in[7];
    const float* ae0  = (const float*)d_in[8];
    const float* b0   = (const float*)d_in[9];
    const float* w1   = (const float*)d_in[10];
    const float* as1  = (const float*)d_in[11];
    const float* ad1  = (const float*)d_in[12];
    const float* we1  = (const float*)d_in[13];
    const float* ae1  = (const float*)d_in[14];
    const float* b1   = (const float*)d_in[15];

    const int N = in_sizes[0] / 64;
    const int E = in_sizes[1] / 2;
    const int NB = (N + BSZ - 1) >> BBITS;   // 196 <= MAXB

    char* ws = (char*)d_ws;
    size_t o = 0;
    auto alloc = [&](size_t bytes) { size_t r = o; o = (o + bytes + 255) & ~(size_t)255; return r; };
    size_t o_bcount   = alloc(4 * 260);
    size_t o_bbase    = alloc(4 * 260);
    size_t o_bcursor  = alloc(4 * 260);
    size_t o_counts10 = alloc(64);
    size_t o_alphaE   = alloc(4 * 88);
    size_t o_rowptr   = alloc((size_t)4 * (N + 1));
    size_t o_staging  = alloc((size_t)4 * E);
    size_t o_packed   = alloc((size_t)4 * E);
    size_t o_h0       = alloc((size_t)4 * N * 64);   // reused as h1 ([N,32]) for layer 1
    size_t o_x1       = alloc((size_t)4 * N * 64);
    size_t o_ssrc     = alloc((size_t)4 * N * 4);
    size_t o_sdst     = alloc((size_t)4 * N * 4);
    (void)ws_size;

    int*   bcount   = (int*)(ws + o_bcount);
    int*   bbase    = (int*)(ws + o_bbase);
    int*   bcursor  = (int*)(ws + o_bcursor);
    int*   counts10 = (int*)(ws + o_counts10);
    float* alphaE   = (float*)(ws + o_alphaE);
    int*   rowptr   = (int*)(ws + o_rowptr);
    int*   staging  = (int*)(ws + o_staging);
    int*   packed   = (int*)(ws + o_packed);
    float* h0       = (float*)(ws + o_h0);
    float* x1       = (float*)(ws + o_x1);
    float* ssrc     = (float*)(ws + o_ssrc);
    float* sdst     = (float*)(ws + o_sdst);
    float* outp     = (float*)d_out;

    hipMemsetAsync(bcount, 0, 4 * 260, stream);
    hipMemsetAsync(counts10, 0, 64, stream);

    int egrid = (E + 4095) / 4096;
    k1_bucket_hist<<<egrid, 256, 0, stream>>>(ei, ety, E, bcount, counts10);
    alphaE_kernel<<<1, 128, 0, stream>>>(emb, we0, ae0, we1, ae1, counts10, E, alphaE);
    k2_scan<<<1, 256, 0, stream>>>(bcount, NB, bbase, bcursor, rowptr, N, E);
    k3_bucket_scatter<<<egrid, 256, 0, stream>>>(ei, ety, E, bcursor, staging);
    k4_bucket_build<<<NB, 512, 0, stream>>>(bbase, staging, N, rowptr, packed);

    int ngrid32 = (N + 31) / 32;
    int tgrid = (N * 4 + 255) / 256;

    // Layer 0: in=64, H=4, C=16
    gemm_kernel<64><<<ngrid32, 256, 0, stream>>>(x, w0, N, h0);
    score_kernel<16><<<tgrid, 256, 0, stream>>>(h0, as0, ad0, N, ssrc, sdst);
    agg_kernel<16, true><<<tgrid, 256, 0, stream>>>(rowptr, packed, h0, ssrc, sdst,
                                                    alphaE, b0, N, x1);
    // Layer 1: in=64, H=4, C=8
    gemm_kernel<32><<<ngrid32, 256, 0, stream>>>(x1, w1, N, h0);
    score_kernel<8><<<tgrid, 256, 0, stream>>>(h0, as1, ad1, N, ssrc, sdst);
    agg_kernel<8, false><<<tgrid, 256, 0, stream>>>(rowptr, packed, h0, ssrc, sdst,
                                                    alphaE + 44, b1, N, outp);
}

// Round 3
// 330.682 us; speedup vs baseline: 2.0589x; 1.2269x over previous
//
#include <hip/hip_runtime.h>
#include <hip/hip_fp16.h>
#include <cstdint>

#define LRELU(a) ((a) > 0.f ? (a) : 0.2f * (a))
#define BBITS 9                      // 512 nodes per bucket
#define BSZ   (1 << BBITS)
#define MAXB  256                    // max buckets (N=100000 -> 196)

// ---------------- K1: bucket histogram + edge-type histogram ----------------
__global__ __launch_bounds__(256) void k1_bucket_hist(const int* __restrict__ ei,
                                                      const int* __restrict__ ety, int E,
                                                      int* __restrict__ bcount,
                                                      int* __restrict__ counts10) {
    __shared__ int lh[MAXB];
    __shared__ int lt[16];
    int t = threadIdx.x;
    for (int i = t; i < MAXB; i += 256) lh[i] = 0;
    if (t < 16) lt[t] = 0;
    __syncthreads();
    int base = blockIdx.x * 4096;
    int cnt = min(4096, E - base);
    for (int i = t; i < cnt; i += 256) {
        atomicAdd(&lh[ei[E + base + i] >> BBITS], 1);
        atomicAdd(&lt[ety[base + i]], 1);
    }
    __syncthreads();
    for (int i = t; i < MAXB; i += 256) if (lh[i]) atomicAdd(&bcount[i], lh[i]);
    if (t < 16 && lt[t]) atomicAdd(&counts10[t], lt[t]);
}

// ---------------- K2: scan bucket counts (one block) ----------------
__global__ __launch_bounds__(256) void k2_scan(const int* __restrict__ bcount, int NB,
                                               int* __restrict__ bbase,
                                               int* __restrict__ bcursor,
                                               int* __restrict__ rowptr, int N, int E) {
    __shared__ int sc[256], orig[256];
    int t = threadIdx.x;
    int v = (t < NB) ? bcount[t] : 0;
    orig[t] = v;
    sc[t] = v;
    __syncthreads();
    for (int off = 1; off < 256; off <<= 1) {
        int a = (t >= off) ? sc[t - off] : 0;
        __syncthreads();
        sc[t] += a;
        __syncthreads();
    }
    int ex = sc[t] - orig[t];
    bbase[t] = ex;
    bcursor[t] = ex;
    if (t == 0) rowptr[N] = E;
}

// ---------------- K3: coarse-bucket scatter with chunked coalesced append ----------------
__global__ __launch_bounds__(256) void k3_bucket_scatter(const int* __restrict__ ei,
                                                         const int* __restrict__ ety, int E,
                                                         int* __restrict__ bcursor,
                                                         int* __restrict__ staging) {
    __shared__ int ent[4096];
    __shared__ unsigned char ebb[4096];
    __shared__ int lh[MAXB], lstart[MAXB], lcur[MAXB], cbase[MAXB], sc[MAXB];
    int t = threadIdx.x;
    lh[t] = 0;
    __syncthreads();
    int base = blockIdx.x * 4096;
    int cnt = min(4096, E - base);
    for (int i = t; i < cnt; i += 256) atomicAdd(&lh[ei[E + base + i] >> BBITS], 1);
    __syncthreads();
    sc[t] = lh[t];
    __syncthreads();
    for (int off = 1; off < 256; off <<= 1) {
        int a = (t >= off) ? sc[t - off] : 0;
        __syncthreads();
        sc[t] += a;
        __syncthreads();
    }
    lstart[t] = sc[t] - lh[t];
    int c = lh[t];
    cbase[t] = c ? atomicAdd(&bcursor[t], c) : 0;
    lcur[t] = sc[t] - lh[t];
    __syncthreads();
    for (int i = t; i < cnt; i += 256) {
        int s = ei[base + i], d = ei[E + base + i], ty = ety[base + i];
        int b = d >> BBITS;
        int pos = atomicAdd(&lcur[b], 1);
        ent[pos] = s | (ty << 17) | ((d & (BSZ - 1)) << 21);
        ebb[pos] = (unsigned char)b;
    }
    __syncthreads();
    for (int i = t; i < cnt; i += 256) {
        int b = ebb[i];
        staging[cbase[b] + (i - lstart[b])] = ent[i];
    }
}

// ---------------- K4: per-bucket CSR build ----------------
__global__ __launch_bounds__(512) void k4_bucket_build(const int* __restrict__ bbase,
                                                       const int* __restrict__ staging, int N,
                                                       int* __restrict__ rowptr,
                                                       int* __restrict__ packed) {
    __shared__ int lcnt[BSZ], lsc[BSZ], lcur[BSZ];
    int b = blockIdx.x;
    int t = threadIdx.x;
    int base = bbase[b], cnt = bbase[b + 1] - base;
    int n0 = b << BBITS;
    lcnt[t] = 0;
    __syncthreads();
    for (int i = t; i < cnt; i += 512) atomicAdd(&lcnt[staging[base + i] >> 21], 1);
    __syncthreads();
    lsc[t] = lcnt[t];
    __syncthreads();
    for (int off = 1; off < BSZ; off <<= 1) {
        int a = (t >= off) ? lsc[t - off] : 0;
        __syncthreads();
        lsc[t] += a;
        __syncthreads();
    }
    int lstart = lsc[t] - lcnt[t];
    lcur[t] = lstart;
    int node = n0 + t;
    if (node < N) rowptr[node] = base + lstart;
    __syncthreads();
    for (int i = t; i < cnt; i += 512) {
        int entry = staging[base + i];
        int pos = atomicAdd(&lcur[entry >> 21], 1);
        packed[base + pos] = entry & 0x1FFFFF;
    }
}

// ---------------- per-edge-type attention-logit table ----------------
__global__ void alphaE_kernel(const float* __restrict__ emb,
                              const float* __restrict__ w0, const float* __restrict__ ae0,
                              const float* __restrict__ w1, const float* __restrict__ ae1,
                              const int* __restrict__ counts10, int E,
                              float* __restrict__ alphaE) {
    int t = threadIdx.x;
    __shared__ float tmp[88];
    if (t < 80) {
        int l = t / 40, r = t % 40, ty = r >> 2, h = r & 3;
        const float* w = l ? w1 : w0;
        const float* ae = l ? ae1 : ae0;
        int C = l ? 8 : 16;
        const float* ev = emb + ty * 16;
        float val = 0.f;
        for (int c = 0; c < C; ++c) {
            const float* wr = w + (h * C + c) * 16;
            float s = 0.f;
            for (int d = 0; d < 16; ++d) s += wr[d] * ev[d];
            val += s * ae[h * C + c];
        }
        tmp[l * 44 + ty * 4 + h] = val;
        alphaE[l * 44 + ty * 4 + h] = val;
    }
    __syncthreads();
    if (t < 8) {
        int l = t >> 2, h = t & 3;
        float s = 0.f;
        for (int ty = 0; ty < 10; ++ty) s += (float)counts10[ty] * tmp[l * 44 + ty * 4 + h];
        alphaE[l * 44 + 40 + h] = s / (float)E;
    }
}

// ---------------- h = x @ W^T, output fp16 ----------------
template <int OUT>
__global__ __launch_bounds__(256) void gemm_kernel(const float* __restrict__ x,
                                                   const float* __restrict__ W, int N,
                                                   __half* __restrict__ out) {
    __shared__ float wt[64 * (OUT + 1)];
    __shared__ float xs[32 * 64];
    int t = threadIdx.x;
    for (int idx = t; idx < OUT * 64; idx += 256) {
        int j = idx >> 6, k = idx & 63;
        wt[k * (OUT + 1) + j] = W[idx];
    }
    int rowbase = blockIdx.x * 32;
    int nrows = min(32, N - rowbase);
    for (int idx = t; idx < nrows * 64; idx += 256) xs[idx] = x[rowbase * 64 + idx];
    __syncthreads();
    int j = t % OUT;
    int rg = t / OUT;
    const int NG = 256 / OUT;
    for (int r = rg; r < nrows; r += NG) {
        float acc = 0.f;
        const float* xr = xs + r * 64;
#pragma unroll
        for (int k = 0; k < 64; ++k) acc += xr[k] * wt[k * (OUT + 1) + j];
        out[(size_t)(rowbase + r) * OUT + j] = __float2half(acc);
    }
}

// ---------------- per-(node,head) attention scores (fp16 h) ----------------
template <int C>
__global__ __launch_bounds__(256) void score_kernel(const __half* __restrict__ h,
                                                    const float* __restrict__ asrc,
                                                    const float* __restrict__ adst, int N,
                                                    float* __restrict__ ssrc,
                                                    float* __restrict__ sdst) {
    int t = blockIdx.x * 256 + threadIdx.x;
    if (t >= N * 4) return;
    int hd = t & 3;
    const __half2* hr = (const __half2*)(h + (size_t)t * C);
    float s1 = 0.f, s2 = 0.f;
#pragma unroll
    for (int c2 = 0; c2 < C / 2; ++c2) {
        float2 v = __half22float2(hr[c2]);
        s1 += v.x * asrc[hd * C + c2 * 2] + v.y * asrc[hd * C + c2 * 2 + 1];
        s2 += v.x * adst[hd * C + c2 * 2] + v.y * adst[hd * C + c2 * 2 + 1];
    }
    ssrc[t] = s1;
    sdst[t] = s2;
}

__device__ inline void fma_h8(float* acc, float4 v, float ex) {
    const __half2* h2 = (const __half2*)&v;
#pragma unroll
    for (int i = 0; i < 4; ++i) {
        float2 f = __half22float2(h2[i]);
        acc[2 * i]     += ex * f.x;
        acc[2 * i + 1] += ex * f.y;
    }
}

// ---------------- per-(node,head) online-softmax aggregate (fp16 gathers, 2x unroll) ----
template <int C, bool RELU>
__global__ __launch_bounds__(256) void agg_kernel(const int* __restrict__ rowptr,
                                                  const int* __restrict__ packed,
                                                  const __half* __restrict__ hmat,
                                                  const float* __restrict__ ssrc,
                                                  const float* __restrict__ sdst,
                                                  const float* __restrict__ alphaE,
                                                  const float* __restrict__ bias, int N,
                                                  float* __restrict__ out) {
    __shared__ float aE[44];
    if (threadIdx.x < 44) aE[threadIdx.x] = alphaE[threadIdx.x];
    __syncthreads();
    int t = blockIdx.x * 256 + threadIdx.x;
    if (t >= N * 4) return;
    int node = t >> 2, hd = t & 3;
    int beg = rowptr[node], end = rowptr[node + 1];
    float sd = sdst[t];
    float m = LRELU(ssrc[t] + sd + aE[40 + hd]);
    float denom = 1.f;
    float acc[C];
    {
        const float4* hn = (const float4*)(hmat + (size_t)t * C);
#pragma unroll
        for (int c = 0; c < C; ++c) acc[c] = 0.f;
#pragma unroll
        for (int i = 0; i < C / 8; ++i) fma_h8(acc + 8 * i, hn[i], 1.f);
    }
    int k = beg;
    for (; k + 2 <= end; k += 2) {
        int p0 = packed[k], p1 = packed[k + 1];
        int s0 = (p0 & 131071) * 4 + hd, ty0 = (p0 >> 17) & 15;
        int s1 = (p1 & 131071) * 4 + hd, ty1 = (p1 >> 17) & 15;
        float v0 = ssrc[s0], v1 = ssrc[s1];
        const float4* g0 = (const float4*)(hmat + (size_t)s0 * C);
        const float4* g1 = (const float4*)(hmat + (size_t)s1 * C);
        float4 r0[C / 8], r1[C / 8];
#pragma unroll
        for (int i = 0; i < C / 8; ++i) { r0[i] = g0[i]; r1[i] = g1[i]; }
        float a0 = LRELU(v0 + sd + aE[ty0 * 4 + hd]);
        float a1 = LRELU(v1 + sd + aE[ty1 * 4 + hd]);
        float mn = fmaxf(a0, a1);
        if (mn > m) {
            float r = __expf(m - mn);
            denom *= r;
#pragma unroll
            for (int c = 0; c < C; ++c) acc[c] *= r;
            m = mn;
        }
        float e0 = __expf(a0 - m), e1 = __expf(a1 - m);
        denom += e0 + e1;
#pragma unroll
        for (int i = 0; i < C / 8; ++i) { fma_h8(acc + 8 * i, r0[i], e0); fma_h8(acc + 8 * i, r1[i], e1); }
    }
    if (k < end) {
        int p0 = packed[k];
        int s0 = (p0 & 131071) * 4 + hd, ty0 = (p0 >> 17) & 15;
        float v0 = ssrc[s0];
        const float4* g0 = (const float4*)(hmat + (size_t)s0 * C);
        float4 r0[C / 8];
#pragma unroll
        for (int i = 0; i < C / 8; ++i) r0[i] = g0[i];
        float a0 = LRELU(v0 + sd + aE[ty0 * 4 + hd]);
        if (a0 > m) {
            float r = __expf(m - a0);
            denom *= r;
#pragma unroll
            for (int c = 0; c < C; ++c) acc[c] *= r;
            m = a0;
        }
        float e0 = __expf(a0 - m);
        denom += e0;
#pragma unroll
        for (int i = 0; i < C / 8; ++i) fma_h8(acc + 8 * i, r0[i], e0);
    }
    float inv = 1.f / denom;
    float* op = out + (size_t)node * (4 * C) + hd * C;
#pragma unroll
    for (int c = 0; c < C; ++c) {
        float o = fmaf(acc[c], inv, bias[hd * C + c]);
        if (RELU) o = fmaxf(o, 0.f);
        op[c] = o;
    }
}

extern "C" void kernel_launch(void* const* d_in, const int* in_sizes, int n_in,
                              void* d_out, int out_size, void* d_ws, size_t ws_size,
                              hipStream_t stream) {
    const float* x    = (const float*)d_in[0];
    const int*   ei   = (const int*)d_in[1];
    const int*   ety  = (const int*)d_in[2];
    const float* emb  = (const float*)d_in[3];
    const float* w0   = (const float*)d_in[4];
    const float* as0  = (const float*)d_in[5];
    const float* ad0  = (const float*)d_in[6];
    const float* we0  = (const float*)d_in[7];
    const float* ae0  = (const float*)d_in[8];
    const float* b0   = (const float*)d_in[9];
    const float* w1   = (const float*)d_in[10];
    const float* as1  = (const float*)d_in[11];
    const float* ad1  = (const float*)d_in[12];
    const float* we1  = (const float*)d_in[13];
    const float* ae1  = (const float*)d_in[14];
    const float* b1   = (const float*)d_in[15];

    const int N = in_sizes[0] / 64;
    const int E = in_sizes[1] / 2;
    const int NB = (N + BSZ - 1) >> BBITS;

    char* ws = (char*)d_ws;
    size_t o = 0;
    auto alloc = [&](size_t bytes) { size_t r = o; o = (o + bytes + 255) & ~(size_t)255; return r; };
    size_t o_bcount   = alloc(4 * 260);
    size_t o_bbase    = alloc(4 * 260);
    size_t o_bcursor  = alloc(4 * 260);
    size_t o_counts10 = alloc(64);
    size_t o_alphaE   = alloc(4 * 88);
    size_t o_rowptr   = alloc((size_t)4 * (N + 1));
    size_t o_staging  = alloc((size_t)4 * E);
    size_t o_packed   = alloc((size_t)4 * E);
    size_t o_h0       = alloc((size_t)2 * N * 64);   // fp16 h (layer0: N*64, layer1: N*32)
    size_t o_x1       = alloc((size_t)4 * N * 64);
    size_t o_ssrc     = alloc((size_t)4 * N * 4);
    size_t o_sdst     = alloc((size_t)4 * N * 4);
    (void)ws_size;

    int*    bcount   = (int*)(ws + o_bcount);
    int*    bbase    = (int*)(ws + o_bbase);
    int*    bcursor  = (int*)(ws + o_bcursor);
    int*    counts10 = (int*)(ws + o_counts10);
    float*  alphaE   = (float*)(ws + o_alphaE);
    int*    rowptr   = (int*)(ws + o_rowptr);
    int*    staging  = (int*)(ws + o_staging);
    int*    packed   = (int*)(ws + o_packed);
    __half* h0       = (__half*)(ws + o_h0);
    float*  x1       = (float*)(ws + o_x1);
    float*  ssrc     = (float*)(ws + o_ssrc);
    float*  sdst     = (float*)(ws + o_sdst);
    float*  outp     = (float*)d_out;

    hipMemsetAsync(bcount, 0, 4 * 260, stream);
    hipMemsetAsync(counts10, 0, 64, stream);

    int egrid = (E + 4095) / 4096;
    k1_bucket_hist<<<egrid, 256, 0, stream>>>(ei, ety, E, bcount, counts10);
    alphaE_kernel<<<1, 128, 0, stream>>>(emb, we0, ae0, we1, ae1, counts10, E, alphaE);
    k2_scan<<<1, 256, 0, stream>>>(bcount, NB, bbase, bcursor, rowptr, N, E);
    k3_bucket_scatter<<<egrid, 256, 0, stream>>>(ei, ety, E, bcursor, staging);
    k4_bucket_build<<<NB, 512, 0, stream>>>(bbase, staging, N, rowptr, packed);

    int ngrid32 = (N + 31) / 32;
    int tgrid = (N * 4 + 255) / 256;

    // Layer 0: in=64, H=4, C=16
    gemm_kernel<64><<<ngrid32, 256, 0, stream>>>(x, w0, N, h0);
    score_kernel<16><<<tgrid, 256, 0, stream>>>(h0, as0, ad0, N, ssrc, sdst);
    agg_kernel<16, true><<<tgrid, 256, 0, stream>>>(rowptr, packed, h0, ssrc, sdst,
                                                    alphaE, b0, N, x1);
    // Layer 1: in=64, H=4, C=8
    gemm_kernel<32><<<ngrid32, 256, 0, stream>>>(x1, w1, N, h0);
    score_kernel<8><<<tgrid, 256, 0, stream>>>(h0, as1, ad1, N, ssrc, sdst);
    agg_kernel<8, false><<<tgrid, 256, 0, stream>>>(rowptr, packed, h0, ssrc, sdst,
                                                    alphaE + 44, b1, N, outp);
}